// Round 9
// baseline (91.309 us; speedup 1.0000x reference)
//
#include <hip/hip_runtime.h>
#include <hip/hip_bf16.h>
#include <stdint.h>

// AutoregressiveDense: B=8192, D=1024, STRIDE=16, OUT=64, L=64
#define BROWS 8192
#define DDIM  1024
#define LDIM  64
#define ODIM  64
#define NDIM  4096
#define KSTRIDE 16

typedef __attribute__((ext_vector_type(8))) short bf16x8;           // MFMA A/B frag
typedef __attribute__((ext_vector_type(4))) float f32x4;            // MFMA C/D frag
typedef __attribute__((ext_vector_type(8))) unsigned short u16x8;   // 16B bf16 store

static __device__ __forceinline__ unsigned short f2bf(float f) {
    union { float f; uint32_t u; } v; v.f = f;
    uint32_t r = 0x7FFFu + ((v.u >> 16) & 1u);
    return (unsigned short)((v.u + r) >> 16);
}

static __device__ __forceinline__ void async16(const void* g, void* l) {
    __builtin_amdgcn_global_load_lds(
        (const __attribute__((address_space(1))) void*)g,
        (__attribute__((address_space(3))) void*)l, 16, 0, 0);
}

// ---------- prep: masked W' (B^T bf16) only — x conversion is fused into the GEMM ----------
__global__ __launch_bounds__(256) void prep_kernel(const float* __restrict__ W,
                                                   unsigned short* __restrict__ wbt) {
    __shared__ float tile[64][65];
    const int bid = blockIdx.x;
    const int l  = bid >> 4;
    const int d0 = (bid & 15) << 6;
    const int t  = threadIdx.x;
    {
        const int dd = t >> 2;
        const int o4 = (t & 3) << 4;
        const float* src = W + ((size_t)((l << 10) + d0 + dd) << 6) + o4;
        #pragma unroll
        for (int j = 0; j < 4; ++j) {
            float4 v = reinterpret_cast<const float4*>(src)[j];
            tile[dd][o4 + 4 * j + 0] = v.x;
            tile[dd][o4 + 4 * j + 1] = v.y;
            tile[dd][o4 + 4 * j + 2] = v.z;
            tile[dd][o4 + 4 * j + 3] = v.w;
        }
    }
    __syncthreads();
    {
        const int o    = t >> 2;
        const int dloc = (t & 3) << 4;
        const int kmax = l * KSTRIDE;
        unsigned short* dst = wbt + ((size_t)((l << 6) + o) << 10) + d0 + dloc;
        u16x8 r0, r1;
        #pragma unroll
        for (int j = 0; j < 8; ++j) {
            int da = d0 + dloc + j;
            int db = da + 8;
            r0[j] = (da < kmax) ? f2bf(tile[dloc + j][o])     : (unsigned short)0;
            r1[j] = (db < kmax) ? f2bf(tile[dloc + 8 + j][o]) : (unsigned short)0;
        }
        *reinterpret_cast<u16x8*>(dst)     = r0;
        *reinterpret_cast<u16x8*>(dst + 8) = r1;
    }
}

// ---------- main GEMM: 256x128 tile, BK=32, 8 waves (4Mx2N, wave tile 64x64) ----------
// r7 structure (dist-2 triple-buffer, counted vmcnt, raw barrier — best @62.7) with x-cvt
// FUSED into A-staging: read x f32 (L2/L3-resident panels), v_cvt_pk_bf16_f32, ds_write
// into the same linear [row][64B] layout. B stays on global_load_lds. Per iter exactly
// 5 VM ops (4 A-dwordx4 + 1 B-async16) are younger than B(t) => vmcnt(5) before the
// barrier guarantees B(t) landed, independent of compiler load placement; A RAW waits
// are compiler-inserted (loads aged one full iteration ~1300cy > 900cy HBM latency).
// A-writes are write-late (after MFMA) + lgkmcnt(0) before the barrier.
__global__ __launch_bounds__(512) void ar_gemm_kernel(
        const float* __restrict__ x,
        const unsigned short* __restrict__ wbt,
        const float* __restrict__ bias,
        float* __restrict__ out) {
    __shared__ int4 smem[4608];   // 72 KiB: buf p at p*24576 = A[256][64B] + B[128][64B] at +16384
    char* lds = (char*)smem;

    const int s  = blockIdx.x >> 8;            // 4 supertiles of 256 blocks (one generation each)
    const int i  = blockIdx.x & 255;
    const int bm = ((s & 1) << 4) + (i & 15);          // 0..31 (tiles of 256 rows)
    const int bn = ((s < 2) ? 16 : 0) + 15 - (i >> 4); // heavy bn (16..31) first, big nkt first
    const int tid  = threadIdx.x;
    const int lane = tid & 63;
    const int wid  = tid >> 6;
    const int wm   = wid >> 1;                 // 4 M-waves x 2 N-waves, wave tile 64x64
    const int wn   = wid & 1;

    const int nkt = bn + 1;                    // K-tiles of 32

    // A staging: thread -> (row = tid>>1, half h = tid&1): 16 f32 in, 16 bf16 (32B) out
    const int rowA = tid >> 1, hA = tid & 1;
    const float* gA = x + ((size_t)((bm << 8) + rowA) << 10) + (hA << 4);
    const int ldsAoff = rowA * 64 + hA * 32;
    // B staging: thread -> row tid>>2, 16B chunk tid&3 (linear, matches gload_lds)
    const char* gB = (const char*)wbt + ((size_t)((bn << 7) + (tid >> 2)) << 11) + ((tid & 3) << 4);

    // fragment read offsets (bytes): row = (lane&15), k-granule by lane>>4 (r1-proven layout)
    const int aoff = ((wm << 6) + (lane & 15)) * 64 + ((lane >> 4) << 4);
    const int boff = 16384 + ((wn << 6) + (lane & 15)) * 64 + ((lane >> 4) << 4);

    f32x4 acc[4][4];
    #pragma unroll
    for (int m = 0; m < 4; ++m)
        #pragma unroll
        for (int n = 0; n < 4; ++n)
            acc[m][n] = (f32x4)(0.f);

    auto loadA = [&](int t, float4* r) {       // 4x dwordx4 f32 (64B), clamped source
        const float* g = gA + ((size_t)(t < nkt ? t : nkt - 1) << 5);
        #pragma unroll
        for (int j = 0; j < 4; ++j)
            r[j] = *reinterpret_cast<const float4*>(g + 4 * j);
    };
    auto cvtwriteA = [&](int t, const float4* r) {   // 8x v_cvt_pk_bf16_f32 + 2x ds_write_b128
        char* dst = lds + (t % 3) * 24576 + ldsAoff;
        const float* f = reinterpret_cast<const float*>(r);
        int p[8];
        #pragma unroll
        for (int j = 0; j < 8; ++j)
            asm("v_cvt_pk_bf16_f32 %0, %1, %2" : "=v"(p[j]) : "v"(f[2 * j]), "v"(f[2 * j + 1]));
        *reinterpret_cast<int4*>(dst)      = make_int4(p[0], p[1], p[2], p[3]);
        *reinterpret_cast<int4*>(dst + 16) = make_int4(p[4], p[5], p[6], p[7]);
    };
    auto stageB = [&](int t) {                 // 1x global_load_lds (16B), clamped source
        const int kb = (t < nkt ? t : nkt - 1) << 6;
        async16(gB + kb, lds + (t % 3) * 24576 + 16384 + tid * 16);
    };

    // prologue: A(0) reg-load + B(0); consume A(0) -> buf0; A(1)+B(1) in flight
    float4 a0[4], ar[4];
    loadA(0, a0); stageB(0);
    loadA(1, ar); stageB(1);
    cvtwriteA(0, a0);                                   // compiler waits A(0) loads
    asm volatile("s_waitcnt vmcnt(5)" ::: "memory");    // B(0) landed (A(1)x4+B(1)=5 younger)
    asm volatile("s_waitcnt lgkmcnt(0)" ::: "memory");  // A(0) ds_writes drained
    __builtin_amdgcn_sched_barrier(0);
    __builtin_amdgcn_s_barrier();
    __builtin_amdgcn_sched_barrier(0);

    for (int t = 0; t < nkt; ++t) {
        // buf[t%3] ready: A written iter t-1 (+lgkm0+barrier), B landed (vmcnt5 pre-barrier)
        stageB(t + 2);                                  // WAR ok: readers drained at iter t-1
        float4 an[4];
        loadA(t + 2, an);
        const char* pb = lds + (t % 3) * 24576;
        bf16x8 afr[4], bfr[4];
        #pragma unroll
        for (int m = 0; m < 4; ++m)
            afr[m] = *reinterpret_cast<const bf16x8*>(pb + aoff + m * 1024);
        #pragma unroll
        for (int n = 0; n < 4; ++n)
            bfr[n] = *reinterpret_cast<const bf16x8*>(pb + boff + n * 1024);
        __builtin_amdgcn_s_setprio(1);
        #pragma unroll
        for (int m = 0; m < 4; ++m)
            #pragma unroll
            for (int n = 0; n < 4; ++n)
                acc[m][n] = __builtin_amdgcn_mfma_f32_16x16x32_bf16(afr[m], bfr[n], acc[m][n], 0, 0, 0);
        __builtin_amdgcn_s_setprio(0);
        cvtwriteA(t + 1, ar);                           // write-late; WAR ok (readers at t-2)
        #pragma unroll
        for (int j = 0; j < 4; ++j) ar[j] = an[j];      // rotate pending A regs
        asm volatile("s_waitcnt lgkmcnt(0)" ::: "memory");  // ds_writes + frag reads drained
        if (t + 1 < nkt) {
            asm volatile("s_waitcnt vmcnt(5)" ::: "memory"); // B(t+1) landed (5 younger ops)
            __builtin_amdgcn_sched_barrier(0);
            __builtin_amdgcn_s_barrier();
            __builtin_amdgcn_sched_barrier(0);
        }
    }
    asm volatile("s_waitcnt vmcnt(0)" ::: "memory");    // drain clamped tail stages

    // epilogue: C/D layout col=lane&15, row=(lane>>4)*4+j; add bias in f32
    const int crow = (bm << 8) + (wm << 6) + ((lane >> 4) << 2);
    const int ccol = (bn << 7) + (wn << 6) + (lane & 15);
    float bv[4];
    #pragma unroll
    for (int n = 0; n < 4; ++n) bv[n] = bias[ccol + n * 16];
    #pragma unroll
    for (int m = 0; m < 4; ++m)
        #pragma unroll
        for (int n = 0; n < 4; ++n)
            #pragma unroll
            for (int j = 0; j < 4; ++j)
                out[(size_t)(crow + m * 16 + j) * NDIM + ccol + n * 16] = acc[m][n][j] + bv[n];
}

// ---------- fallback: naive f32 (used only if workspace too small) ----------
__global__ __launch_bounds__(256) void naive_kernel(const float* __restrict__ x,
                                                    const float* __restrict__ W,
                                                    const float* __restrict__ bias,
                                                    float* __restrict__ out) {
    size_t idx = (size_t)blockIdx.x * 256 + threadIdx.x;
    if (idx >= (size_t)BROWS * NDIM) return;
    int m = (int)(idx >> 12);
    int n = (int)(idx & 4095);
    int l = n >> 6;
    int o = n & 63;
    int kmax = l * KSTRIDE;
    float s = bias[n];
    const float* xr = x + (size_t)m * DDIM;
    const float* wp = W + ((size_t)l << 16) + o;
    for (int d = 0; d < kmax; ++d) s += xr[d] * wp[(size_t)d << 6];
    out[idx] = s;
}

extern "C" void kernel_launch(void* const* d_in, const int* in_sizes, int n_in,
                              void* d_out, int out_size, void* d_ws, size_t ws_size,
                              hipStream_t stream) {
    const float* x = (const float*)d_in[0];
    const float* W = (const float*)d_in[1];
    const float* b = (const float*)d_in[2];
    float* out = (float*)d_out;

    const size_t need = (size_t)NDIM * DDIM * sizeof(unsigned short);   // 8.4 MB
    if (ws_size < need) {
        int total = BROWS * NDIM;
        naive_kernel<<<(total + 255) / 256, 256, 0, stream>>>(x, W, b, out);
        return;
    }
    unsigned short* wbt = (unsigned short*)d_ws;          // bf16 W' [4096][1024]

    prep_kernel<<<1024, 256, 0, stream>>>(W, wbt);
    ar_gemm_kernel<<<1024, 512, 0, stream>>>(x, wbt, b, out);
}

// Round 10
// 63.138 us; speedup vs baseline: 1.4462x; 1.4462x over previous
//
#include <hip/hip_runtime.h>
#include <hip/hip_bf16.h>
#include <stdint.h>

// AutoregressiveDense: B=8192, D=1024, STRIDE=16, OUT=64, L=64
#define BROWS 8192
#define DDIM  1024
#define LDIM  64
#define ODIM  64
#define NDIM  4096
#define KSTRIDE 16

typedef __attribute__((ext_vector_type(8))) short bf16x8;           // MFMA A/B frag
typedef __attribute__((ext_vector_type(4))) float f32x4;            // MFMA C/D frag
typedef __attribute__((ext_vector_type(8))) unsigned short u16x8;   // 16B bf16 store

static __device__ __forceinline__ unsigned short f2bf(float f) {
    union { float f; uint32_t u; } v; v.f = f;
    uint32_t r = 0x7FFFu + ((v.u >> 16) & 1u);
    return (unsigned short)((v.u + r) >> 16);
}

static __device__ __forceinline__ void async16(const void* g, void* l) {
    __builtin_amdgcn_global_load_lds(
        (const __attribute__((address_space(1))) void*)g,
        (__attribute__((address_space(3))) void*)l, 16, 0, 0);
}

// ---------- merged prep: blocks [0,1024) build masked W' (B^T bf16), blocks [1024,5120) convert x ----------
__global__ __launch_bounds__(256) void prep_kernel(const float* __restrict__ x,
                                                   const float* __restrict__ W,
                                                   unsigned short* __restrict__ xb,
                                                   unsigned short* __restrict__ wbt) {
    const int bid = blockIdx.x;
    if (bid < 1024) {
        // W [L][D][O] f32 -> masked bf16 W' [N=l*64+o][K=d], zero for d >= l*16
        __shared__ float tile[64][65];
        const int l  = bid >> 4;
        const int d0 = (bid & 15) << 6;
        const int t  = threadIdx.x;
        {
            const int dd = t >> 2;
            const int o4 = (t & 3) << 4;
            const float* src = W + ((size_t)((l << 10) + d0 + dd) << 6) + o4;
            #pragma unroll
            for (int j = 0; j < 4; ++j) {
                float4 v = reinterpret_cast<const float4*>(src)[j];
                tile[dd][o4 + 4 * j + 0] = v.x;
                tile[dd][o4 + 4 * j + 1] = v.y;
                tile[dd][o4 + 4 * j + 2] = v.z;
                tile[dd][o4 + 4 * j + 3] = v.w;
            }
        }
        __syncthreads();
        {
            const int o    = t >> 2;
            const int dloc = (t & 3) << 4;
            const int kmax = l * KSTRIDE;
            unsigned short* dst = wbt + ((size_t)((l << 6) + o) << 10) + d0 + dloc;
            u16x8 r0, r1;
            #pragma unroll
            for (int j = 0; j < 8; ++j) {
                int da = d0 + dloc + j;
                int db = da + 8;
                r0[j] = (da < kmax) ? f2bf(tile[dloc + j][o])     : (unsigned short)0;
                r1[j] = (db < kmax) ? f2bf(tile[dloc + 8 + j][o]) : (unsigned short)0;
            }
            *reinterpret_cast<u16x8*>(dst)     = r0;
            *reinterpret_cast<u16x8*>(dst + 8) = r1;
        }
    } else {
        int i = (bid - 1024) * 256 + threadIdx.x;
        const float4* xf = reinterpret_cast<const float4*>(x);
        float4 v0 = xf[2 * i];
        float4 v1 = xf[2 * i + 1];
        u16x8 r;
        r[0] = f2bf(v0.x); r[1] = f2bf(v0.y); r[2] = f2bf(v0.z); r[3] = f2bf(v0.w);
        r[4] = f2bf(v1.x); r[5] = f2bf(v1.y); r[6] = f2bf(v1.z); r[7] = f2bf(v1.w);
        reinterpret_cast<u16x8*>(xb)[i] = r;
    }
}

// ---------- main GEMM: 256x128 tile, BK=32, 8 waves (4Mx2N, wave tile 64x64) ----------
// r7 structure (dist-2 triple-buffer, counted vmcnt, raw barrier; best @62.7) + the r9
// diagnosis fix: the frag ds_read_b128 pattern (addr=row*64, rows=lane&15) was an 8-WAY
// BANK CONFLICT in r1-r9 (bank-start (16*row)%32 = {0,16}; 6.6M conflicts/dispatch
// measured r9) — the hidden reason all r5-r8 pipeline variants were neutral: LDS-read
// serialization was the critical path. Fix per rule #21 (both-sides-or-neither):
// LDS granule col c' = c ^ ((row>>1)&3) within each 64B row, applied as pre-swizzled
// GLOBAL source (stage thread t loads chunk (t&3)^((t>>3)&3); LDS dest stays linear,
// matching gload_lds) + the same XOR in frag-read offsets ((lane>>4)^((lane>>1)&3);
// m*16/n*16 row steps are 0 mod 4 rows so one per-lane constant serves all frags).
// Result: 16-lane granule groups hit bank-starts {0,4,8,12}/{16,20,24,28} 2x each ->
// 2-way = free (m136). LDS 3 x 24KB = 72KB -> 2 blocks/CU. acc[4][4]=64 regs.
__global__ __launch_bounds__(512, 2) void ar_gemm_kernel(
        const unsigned short* __restrict__ xb,
        const unsigned short* __restrict__ wbt,
        const float* __restrict__ bias,
        float* __restrict__ out) {
    __shared__ char lds[73728];   // buf p at p*24576: A[256][64B] at +0, B[128][64B] at +16384

    const int s  = blockIdx.x >> 8;            // 4 supertiles of 256 blocks (one generation each)
    const int i  = blockIdx.x & 255;
    const int bm = ((s & 1) << 4) + (i & 15);          // 0..31 (tiles of 256 rows)
    const int bn = ((s < 2) ? 16 : 0) + 15 - (i >> 4); // heavy bn (16..31) first, big nkt first
    const int tid  = threadIdx.x;
    const int lane = tid & 63;
    const int wid  = tid >> 6;
    const int wm   = wid >> 1;                 // 4 M-waves x 2 N-waves, wave tile 64x64
    const int wn   = wid & 1;

    const int nkt = bn + 1;                    // K-tiles of 32

    // staging: thread t fills LDS-linear slot t*16 (row t>>2, granule t&3); global source
    // chunk is INVERSE-swizzled so LDS(row,c') = global(row, c'^((row>>1)&3))
    const int cb = (((tid & 3) ^ ((tid >> 3) & 3)) << 4);
    const char* gA = (const char*)xb  + ((size_t)((bm << 8) + (tid >> 2)) << 11) + cb;
    const char* gB = (const char*)wbt + ((size_t)((bn << 7) + (tid >> 2)) << 11) + cb;

    // frag reads: row = (lane&15) (+64*wm/wn), want global granule g=lane>>4 -> read LDS
    // granule g ^ ((row>>1)&3); ( (lane&15)>>1 )&3 == (lane>>1)&3
    const int sw   = (lane >> 1) & 3;
    const int aoff = ((wm << 6) + (lane & 15)) * 64 + (((lane >> 4) ^ sw) << 4);
    const int boff = 16384 + ((wn << 6) + (lane & 15)) * 64 + (((lane >> 4) ^ sw) << 4);

    f32x4 acc[4][4];
    #pragma unroll
    for (int m = 0; m < 4; ++m)
        #pragma unroll
        for (int n = 0; n < 4; ++n)
            acc[m][n] = (f32x4)(0.f);

    // stage K-tile t into buffer t%3 (3 asyncs/thread). Clamp source for t>=nkt (dest unused).
    auto stage = [&](int t) {
        const int kb = (t < nkt ? t : nkt - 1) << 6;
        char* l = lds + (t % 3) * 24576 + tid * 16;
        async16(gA + kb, l);
        async16(gA + ((size_t)128 << 11) + kb, l + 8192);   // rows 128-255: (row>>1)&3 unchanged
        async16(gB + kb, l + 16384);
    };

    stage(0);
    stage(1);                                  // 6 loads in flight

    for (int t = 0; t < nkt; ++t) {
        asm volatile("s_waitcnt vmcnt(3)" ::: "memory");   // tile t landed; t+1 stays in flight
        __builtin_amdgcn_sched_barrier(0);
        __builtin_amdgcn_s_barrier();                      // raw: no vmcnt(0) drain
        stage(t + 2);                                      // writes buf[(t-1)%3]; readers passed barrier
        const char* pb = lds + (t % 3) * 24576;
        bf16x8 a[4], b[4];
        #pragma unroll
        for (int m = 0; m < 4; ++m)
            a[m] = *reinterpret_cast<const bf16x8*>(pb + aoff + m * 1024);
        #pragma unroll
        for (int n = 0; n < 4; ++n)
            b[n] = *reinterpret_cast<const bf16x8*>(pb + boff + n * 1024);
        #pragma unroll
        for (int m = 0; m < 4; ++m)
            #pragma unroll
            for (int n = 0; n < 4; ++n)
                acc[m][n] = __builtin_amdgcn_mfma_f32_16x16x32_bf16(a[m], b[n], acc[m][n], 0, 0, 0);
    }
    asm volatile("s_waitcnt vmcnt(0)" ::: "memory");       // drain clamped tails before LDS dealloc

    // epilogue: C/D layout col=lane&15, row=(lane>>4)*4+j; add bias in f32
    const int crow = (bm << 8) + (wm << 6) + ((lane >> 4) << 2);
    const int ccol = (bn << 7) + (wn << 6) + (lane & 15);
    float bv[4];
    #pragma unroll
    for (int n = 0; n < 4; ++n) bv[n] = bias[ccol + n * 16];
    #pragma unroll
    for (int m = 0; m < 4; ++m)
        #pragma unroll
        for (int n = 0; n < 4; ++n)
            #pragma unroll
            for (int j = 0; j < 4; ++j)
                out[(size_t)(crow + m * 16 + j) * NDIM + ccol + n * 16] = acc[m][n][j] + bv[n];
}

// ---------- fallback: naive f32 (used only if workspace too small) ----------
__global__ __launch_bounds__(256) void naive_kernel(const float* __restrict__ x,
                                                    const float* __restrict__ W,
                                                    const float* __restrict__ bias,
                                                    float* __restrict__ out) {
    size_t idx = (size_t)blockIdx.x * 256 + threadIdx.x;
    if (idx >= (size_t)BROWS * NDIM) return;
    int m = (int)(idx >> 12);
    int n = (int)(idx & 4095);
    int l = n >> 6;
    int o = n & 63;
    int kmax = l * KSTRIDE;
    float s = bias[n];
    const float* xr = x + (size_t)m * DDIM;
    const float* wp = W + ((size_t)l << 16) + o;
    for (int d = 0; d < kmax; ++d) s += xr[d] * wp[(size_t)d << 6];
    out[idx] = s;
}

extern "C" void kernel_launch(void* const* d_in, const int* in_sizes, int n_in,
                              void* d_out, int out_size, void* d_ws, size_t ws_size,
                              hipStream_t stream) {
    const float* x = (const float*)d_in[0];
    const float* W = (const float*)d_in[1];
    const float* b = (const float*)d_in[2];
    float* out = (float*)d_out;

    const size_t need = ((size_t)BROWS * DDIM + (size_t)NDIM * DDIM) * sizeof(unsigned short);
    if (ws_size < need) {
        int total = BROWS * NDIM;
        naive_kernel<<<(total + 255) / 256, 256, 0, stream>>>(x, W, b, out);
        return;
    }
    unsigned short* xbuf = (unsigned short*)d_ws;             // bf16 x  [8192][1024]
    unsigned short* wbt  = xbuf + (size_t)BROWS * DDIM;       // bf16 W' [4096][1024]

    prep_kernel<<<5120, 256, 0, stream>>>(x, W, xbuf, wbt);
    ar_gemm_kernel<<<1024, 512, 0, stream>>>(xbuf, wbt, b, out);
}